// Round 2
// baseline (140.056 us; speedup 1.0000x reference)
//
#include <hip/hip_runtime.h>

typedef __attribute__((ext_vector_type(4))) float f32x4;
typedef __attribute__((ext_vector_type(8))) short s16x8;
typedef __attribute__((ext_vector_type(4))) short s16x4;
typedef __attribute__((ext_vector_type(8))) __bf16 bf16x8;

#define B_ 64
#define LQ_ 32
#define LP_ 256
#define H_ 768
#define D_ 128

__device__ __forceinline__ short cvt_bf16(float f) {
  unsigned u = __builtin_bit_cast(unsigned, f);
  unsigned r = (u + 0x7fffu + ((u >> 16) & 1u)) >> 16;
  return (short)r;
}

__device__ __forceinline__ f32x4 mfma16(s16x8 a, s16x8 b, f32x4 c) {
  return __builtin_amdgcn_mfma_f32_16x16x32_bf16(
      __builtin_bit_cast(bf16x8, a), __builtin_bit_cast(bf16x8, b), c, 0, 0, 0);
}

// ---------------- K1: W [768][128] f32 -> Wt [128][768] bf16 ----------------
__global__ __launch_bounds__(256) void k_wt(const float* __restrict__ W,
                                            short* __restrict__ Wt) {
  __shared__ float tile[32][33];
  int k0 = blockIdx.x * 32, n0 = blockIdx.y * 32;
  int t = threadIdx.x;
  int r = t >> 3, c4 = (t & 7) << 2;
  f32x4 v = *(const f32x4*)(W + (size_t)(k0 + r) * D_ + n0 + c4);
  tile[r][c4 + 0] = v[0]; tile[r][c4 + 1] = v[1];
  tile[r][c4 + 2] = v[2]; tile[r][c4 + 3] = v[3];
  __syncthreads();
  s16x4 o;
  o[0] = cvt_bf16(tile[c4 + 0][r]);
  o[1] = cvt_bf16(tile[c4 + 1][r]);
  o[2] = cvt_bf16(tile[c4 + 2][r]);
  o[3] = cvt_bf16(tile[c4 + 3][r]);
  *(s16x4*)(Wt + (size_t)(n0 + r) * H_ + k0 + c4) = o;
}

// ---------------- K2: masks (int32) -> f32 {0, -inf} ----------------
__global__ __launch_bounds__(256) void k_maskf(const int* __restrict__ pm,
                                               const int* __restrict__ nm,
                                               float* __restrict__ mf) {
  int i = blockIdx.x * 256 + threadIdx.x;  // 64 blocks * 256 = 16384
  float ninf = -__builtin_inff();
  mf[i]         = pm[i] ? 0.f : ninf;
  mf[16384 + i] = nm[i] ? 0.f : ninf;
}

// ---------------- K3: projection GEMM x = h@W + b (bf16 MFMA) ----------------
// grid: 544 blocks (32 q-tiles, 256 p-tiles, 256 n-tiles), 256 threads.
// tile BM=64 x BN=128, BK=32; 4 waves 2x2, per-wave 32x64 (mi2 x ni4).
__global__ __launch_bounds__(256) void k_proj(
    const float* __restrict__ Hq, const float* __restrict__ Hp, const float* __restrict__ Hn,
    const short* __restrict__ Wt, const float* __restrict__ bias,
    float* __restrict__ Xq, float* __restrict__ Xp, float* __restrict__ Xn) {
  __shared__ short As[64 * 40];   // [64][32] padded to 40 (bank-spread)
  __shared__ short Bs[128 * 40];  // [128][32] padded to 40, stores W^T tile
  int bid = blockIdx.x;
  const float* Hs; float* X; int row0;
  if (bid < 32)       { Hs = Hq; X = Xq; row0 = bid * 64; }
  else if (bid < 288) { Hs = Hp; X = Xp; row0 = (bid - 32) * 64; }
  else                { Hs = Hn; X = Xn; row0 = (bid - 288) * 64; }
  int t = threadIdx.x;
  int lane = t & 63, w = t >> 6;
  int wm = w >> 1, wn = w & 1;
  int lhi = lane >> 4, llo = lane & 15;
  f32x4 acc[2][4] = {};
  int ar = t >> 2, ac = (t & 3) << 3;  // A staging: 4 thr/row, 8 elems each
  int bn = t >> 1, bk = (t & 1) << 4;  // B staging: 2 thr/row, 16 elems each

  for (int k0 = 0; k0 < H_; k0 += 32) {
    const float* asrc = Hs + (size_t)(row0 + ar) * H_ + k0 + ac;
    f32x4 a0 = *(const f32x4*)(asrc);
    f32x4 a1 = *(const f32x4*)(asrc + 4);
    s16x8 av;
    av[0] = cvt_bf16(a0[0]); av[1] = cvt_bf16(a0[1]);
    av[2] = cvt_bf16(a0[2]); av[3] = cvt_bf16(a0[3]);
    av[4] = cvt_bf16(a1[0]); av[5] = cvt_bf16(a1[1]);
    av[6] = cvt_bf16(a1[2]); av[7] = cvt_bf16(a1[3]);
    *(s16x8*)(&As[ar * 40 + ac]) = av;

    const short* bsrc = Wt + (size_t)bn * H_ + k0 + bk;
    s16x8 b0 = *(const s16x8*)(bsrc);
    s16x8 b1 = *(const s16x8*)(bsrc + 8);
    *(s16x8*)(&Bs[bn * 40 + bk]) = b0;
    *(s16x8*)(&Bs[bn * 40 + bk + 8]) = b1;
    __syncthreads();

    s16x8 af[2], bfv[4];
    for (int mi = 0; mi < 2; mi++)
      af[mi] = *(const s16x8*)(&As[(wm * 32 + mi * 16 + llo) * 40 + lhi * 8]);
    for (int ni = 0; ni < 4; ni++)
      bfv[ni] = *(const s16x8*)(&Bs[(wn * 64 + ni * 16 + llo) * 40 + lhi * 8]);
    for (int mi = 0; mi < 2; mi++)
      for (int ni = 0; ni < 4; ni++)
        acc[mi][ni] = mfma16(af[mi], bfv[ni], acc[mi][ni]);
    __syncthreads();
  }
  for (int ni = 0; ni < 4; ni++) {
    int col = wn * 64 + ni * 16 + llo;
    float bv = bias[col];
    for (int mi = 0; mi < 2; mi++)
      for (int r = 0; r < 4; r++) {
        int row = row0 + wm * 32 + mi * 16 + lhi * 4 + r;
        X[(size_t)row * D_ + col] = acc[mi][ni][r] + bv;
      }
  }
}

// ---------------- K4: token-axis norm + normalize -> bf16 ----------------
// grid (64, 3): y selects tensor. 256 threads: 2 token-halves x 128 d.
__global__ __launch_bounds__(256) void k_norm(
    const float* __restrict__ Xq, const float* __restrict__ Xp, const float* __restrict__ Xn,
    short* __restrict__ Vq, short* __restrict__ Vp, short* __restrict__ Vn) {
  __shared__ float ssum[256];
  int b = blockIdx.x;
  const float* X; short* V; int L;
  if (blockIdx.y == 0)      { X = Xq; V = Vq; L = LQ_; }
  else if (blockIdx.y == 1) { X = Xp; V = Vp; L = LP_; }
  else                      { X = Xn; V = Vn; L = LP_; }
  int d = threadIdx.x & 127, h = threadIdx.x >> 7;
  const float* x = X + (size_t)b * L * D_ + d;
  float s = 0.f;
  for (int l = h; l < L; l += 2) { float v = x[(size_t)l * D_]; s += v * v; }
  ssum[threadIdx.x] = s;
  __syncthreads();
  float tot = ssum[d] + ssum[d + 128];
  float inv = 1.0f / fmaxf(sqrtf(tot), 1e-12f);
  short* o = V + (size_t)b * L * D_ + d;
  for (int l = h; l < L; l += 2) o[(size_t)l * D_] = cvt_bf16(x[(size_t)l * D_] * inv);
}

// ---------------- K5: MaxSim ----------------
// grid (16 b-chunks, 64 c, 2 side), 512 threads (8 waves, 2x4).
// Block: S = Q[4b] (128 rows) x P[c] (256 p), K=128. P staged in swizzled LDS.
__global__ __launch_bounds__(512, 4) void k_maxsim(
    const short* __restrict__ QV, const short* __restrict__ PV, const short* __restrict__ NV,
    const float* __restrict__ MF, float* __restrict__ OUT) {
  __shared__ short Ps[LP_ * D_];   // 64 KB, XOR-swizzled rows
  __shared__ float red[4][128];
  int t = threadIdx.x;
  int lane = t & 63, w = t >> 6;
  int wm = w >> 2, wn = w & 3;
  int lhi = lane >> 4, llo = lane & 15;
  int bc = blockIdx.x, c = blockIdx.y, side = blockIdx.z;
  const short* P = side ? NV : PV;
  const float* mfp = MF + side * (B_ * LP_) + c * LP_;

  const short* src = P + (size_t)c * LP_ * D_;
  for (int i = 0; i < 8; i++) {
    int s = i * 512 + t;
    int p = s >> 4, kc = s & 15;
    s16x8 v = *(const s16x8*)(src + (size_t)p * D_ + kc * 8);
    int byteoff = (p * 256 + kc * 16) ^ ((p & 7) << 4);
    *(s16x8*)((char*)Ps + byteoff) = v;
  }
  float mfv[4];
  for (int ni = 0; ni < 4; ni++) mfv[ni] = mfp[wn * 64 + ni * 16 + llo];
  __syncthreads();

  f32x4 acc[4][4] = {};
  const short* qbase = QV + (size_t)bc * 4 * LQ_ * D_;
  for (int ks = 0; ks < 4; ks++) {
    s16x8 af[4], bfv[4];
    for (int mi = 0; mi < 4; mi++) {
      int row = wm * 64 + mi * 16 + llo;  // row -> (b_local = row>>5, q = row&31)
      af[mi] = *(const s16x8*)(qbase + (size_t)row * D_ + ks * 32 + lhi * 8);
    }
    for (int ni = 0; ni < 4; ni++) {
      int p = wn * 64 + ni * 16 + llo;
      int byteoff = (p * 256 + (ks * 32 + lhi * 8) * 2) ^ ((p & 7) << 4);
      bfv[ni] = *(const s16x8*)((char*)Ps + byteoff);
    }
    for (int mi = 0; mi < 4; mi++)
      for (int ni = 0; ni < 4; ni++)
        acc[mi][ni] = mfma16(af[mi], bfv[ni], acc[mi][ni]);
  }

  // masked max over p: per-lane over ni, then across the 16-lane group
  for (int mi = 0; mi < 4; mi++) {
    for (int r = 0; r < 4; r++) {
      float v =          acc[mi][0][r] + mfv[0];
      v = fmaxf(v, acc[mi][1][r] + mfv[1]);
      v = fmaxf(v, acc[mi][2][r] + mfv[2]);
      v = fmaxf(v, acc[mi][3][r] + mfv[3]);
      for (int m = 1; m < 16; m <<= 1) v = fmaxf(v, __shfl_xor(v, m, 64));
      if (llo == r) red[wn][wm * 64 + mi * 16 + lhi * 4 + r] = v;
    }
  }
  __syncthreads();

  // combine the 4 wn-waves, then sum over the 32 q of each batch
  if (t < 128) {
    float v = fmaxf(fmaxf(red[0][t], red[1][t]), fmaxf(red[2][t], red[3][t]));
    for (int m = 1; m < 32; m <<= 1) v += __shfl_xor(v, m, 64);
    if ((t & 31) == 0) {
      int bl = t >> 5;
      OUT[(size_t)(bc * 4 + bl) * 128 + side * 64 + c] = v;
    }
  }
}

extern "C" void kernel_launch(void* const* d_in, const int* in_sizes, int n_in,
                              void* d_out, int out_size, void* d_ws, size_t ws_size,
                              hipStream_t stream) {
  const float* qh = (const float*)d_in[0];
  const float* ph = (const float*)d_in[1];
  const float* nh = (const float*)d_in[2];
  const float* W  = (const float*)d_in[3];
  const float* bias = (const float*)d_in[4];
  const int* pm = (const int*)d_in[5];
  const int* nm = (const int*)d_in[6];
  float* out = (float*)d_out;
  char* ws = (char*)d_ws;

  short* Wt = (short*)(ws + 0x0);        // 128x768 bf16   (192 KB)
  float* xq = (float*)(ws + 0x40000);    // 2048x128 f32   (1 MB)
  float* xp = (float*)(ws + 0x140000);   // 16384x128 f32  (8 MB)
  float* xn = (float*)(ws + 0x940000);   // 16384x128 f32  (8 MB)
  short* qv = (short*)(ws + 0x1140000);  // 2048x128 bf16  (512 KB)
  short* pv = (short*)(ws + 0x11C0000);  // 16384x128 bf16 (4 MB)
  short* nv = (short*)(ws + 0x15C0000);  // 16384x128 bf16 (4 MB)
  float* mf = (float*)(ws + 0x19C0000);  // 2x64x256 f32   (128 KB)

  k_wt<<<dim3(24, 4), 256, 0, stream>>>(W, Wt);
  k_maskf<<<64, 256, 0, stream>>>(pm, nm, mf);
  k_proj<<<544, 256, 0, stream>>>(qh, ph, nh, Wt, bias, xq, xp, xn);
  k_norm<<<dim3(64, 3), 256, 0, stream>>>(xq, xp, xn, qv, pv, nv);
  k_maxsim<<<dim3(16, 64, 2), 512, 0, stream>>>(qv, pv, nv, mf, out);
}

// Round 3
// 64.482 us; speedup vs baseline: 2.1720x; 2.1720x over previous
//
#include <hip/hip_runtime.h>

typedef __attribute__((ext_vector_type(4))) float f32x4;
typedef __attribute__((ext_vector_type(8))) short s16x8;
typedef __attribute__((ext_vector_type(4))) short s16x4;
typedef __attribute__((ext_vector_type(8))) __bf16 bf16x8;

#define B_ 64
#define LQ_ 32
#define LP_ 256
#define H_ 768
#define D_ 128

__device__ __forceinline__ short cvt_bf16(float f) {
  unsigned u = __builtin_bit_cast(unsigned, f);
  unsigned r = (u + 0x7fffu + ((u >> 16) & 1u)) >> 16;
  return (short)r;
}
__device__ __forceinline__ float frombf(short h) {
  unsigned v = ((unsigned)(unsigned short)h) << 16;
  return __builtin_bit_cast(float, v);
}
__device__ __forceinline__ f32x4 mfma16(s16x8 a, s16x8 b, f32x4 c) {
  return __builtin_amdgcn_mfma_f32_16x16x32_bf16(
      __builtin_bit_cast(bf16x8, a), __builtin_bit_cast(bf16x8, b), c, 0, 0, 0);
}

// ---------------- K1: fused pre-work ----------------
// blocks 0..95: W [768][128] f32 -> Wt [128][768] bf16 ; blocks 96..159: masks -> f32
__global__ __launch_bounds__(256) void k_pre(const float* __restrict__ W,
                                             const int* __restrict__ pm,
                                             const int* __restrict__ nm,
                                             short* __restrict__ Wt,
                                             float* __restrict__ mf) {
  __shared__ float tile[32][33];
  int bid = blockIdx.x;
  int t = threadIdx.x;
  if (bid < 96) {
    int k0 = (bid % 24) * 32, n0 = (bid / 24) * 32;
    int r = t >> 3, c4 = (t & 7) << 2;
    f32x4 v = *(const f32x4*)(W + (size_t)(k0 + r) * D_ + n0 + c4);
    tile[r][c4 + 0] = v[0]; tile[r][c4 + 1] = v[1];
    tile[r][c4 + 2] = v[2]; tile[r][c4 + 3] = v[3];
    __syncthreads();
    s16x4 o;
    o[0] = cvt_bf16(tile[c4 + 0][r]);
    o[1] = cvt_bf16(tile[c4 + 1][r]);
    o[2] = cvt_bf16(tile[c4 + 2][r]);
    o[3] = cvt_bf16(tile[c4 + 3][r]);
    *(s16x4*)(Wt + (size_t)(n0 + r) * H_ + k0 + c4) = o;
  } else {
    int i = (bid - 96) * 256 + t;
    float ninf = -__builtin_inff();
    mf[i]         = pm[i] ? 0.f : ninf;
    mf[16384 + i] = nm[i] ? 0.f : ninf;
  }
}

// ---------------- K2: projection GEMM x = h@W + b, fused col-sumsq ----------------
// 1088 blocks (64 q, 512 p, 512 n), 256 thr, BM=32 BN=128 BK=64, 2-phase pipeline.
__global__ __launch_bounds__(256, 4) void k_proj(
    const float* __restrict__ Hq, const float* __restrict__ Hp, const float* __restrict__ Hn,
    const short* __restrict__ Wt, const float* __restrict__ bias,
    short* __restrict__ Xq, short* __restrict__ Xp, short* __restrict__ Xn,
    float* __restrict__ ps) {
  __shared__ short As[32 * 64];   // 4 KB, XOR-swizzled rows (pitch 128 B)
  __shared__ short Bs[128 * 64];  // 16 KB, XOR-swizzled rows
  __shared__ float psum[2][128];
  int bid = blockIdx.x;
  const float* Hs; short* X; int row0;
  if (bid < 64)       { Hs = Hq; X = Xq; row0 = bid * 32; }
  else if (bid < 576) { Hs = Hp; X = Xp; row0 = (bid - 64) * 32; }
  else                { Hs = Hn; X = Xn; row0 = (bid - 576) * 32; }
  int t = threadIdx.x, lane = t & 63, w = t >> 6;
  int wm = w >> 1, wn = w & 1, lhi = lane >> 4, llo = lane & 15;

  // staging addressing
  int ar = t >> 3, akc = (t & 7) << 3;   // A: 8 thr/row, 8 f32 each
  int br = t >> 1, bkc = (t & 1) << 5;   // B: 2 thr/row, 32 bf16 each
  const float* aptr = Hs + (size_t)(row0 + ar) * H_ + akc;
  const short* bptr = Wt + (size_t)br * H_ + bkc;
  int ast = (ar * 128 + akc * 2) ^ ((ar & 7) << 4);
  int bst = (br * 128 + bkc * 2);
  int bswz = ((br & 7) << 4);
  char* Ab = (char*)As; char* Bb = (char*)Bs;

  // fragment read offsets
  int arow = wm * 16 + llo;
  int aoff0 = (arow * 128 + lhi * 16) ^ ((arow & 7) << 4);
  int aoff1 = (arow * 128 + 64 + lhi * 16) ^ ((arow & 7) << 4);
  int boff[4][2];
  for (int ni = 0; ni < 4; ni++) {
    int brow = wn * 64 + ni * 16 + llo;
    boff[ni][0] = (brow * 128 + lhi * 16) ^ ((brow & 7) << 4);
    boff[ni][1] = (brow * 128 + 64 + lhi * 16) ^ ((brow & 7) << 4);
  }

  f32x4 pa0 = *(const f32x4*)(aptr);
  f32x4 pa1 = *(const f32x4*)(aptr + 4);
  s16x8 pb0 = *(const s16x8*)(bptr);
  s16x8 pb1 = *(const s16x8*)(bptr + 8);
  s16x8 pb2 = *(const s16x8*)(bptr + 16);
  s16x8 pb3 = *(const s16x8*)(bptr + 24);

  f32x4 acc[4] = {};
  for (int it = 0; it < 12; ++it) {
    s16x8 av;
    av[0] = cvt_bf16(pa0[0]); av[1] = cvt_bf16(pa0[1]);
    av[2] = cvt_bf16(pa0[2]); av[3] = cvt_bf16(pa0[3]);
    av[4] = cvt_bf16(pa1[0]); av[5] = cvt_bf16(pa1[1]);
    av[6] = cvt_bf16(pa1[2]); av[7] = cvt_bf16(pa1[3]);
    *(s16x8*)(Ab + ast) = av;
    *(s16x8*)(Bb + ((bst +  0) ^ bswz)) = pb0;
    *(s16x8*)(Bb + ((bst + 16) ^ bswz)) = pb1;
    *(s16x8*)(Bb + ((bst + 32) ^ bswz)) = pb2;
    *(s16x8*)(Bb + ((bst + 48) ^ bswz)) = pb3;
    asm volatile("s_waitcnt lgkmcnt(0)" ::: "memory");
    __builtin_amdgcn_s_barrier();
    if (it < 11) {  // prefetch next K-tile; stays in flight across end barrier
      const float* ap = aptr + (it + 1) * 64;
      pa0 = *(const f32x4*)(ap);
      pa1 = *(const f32x4*)(ap + 4);
      const short* bp = bptr + (it + 1) * 64;
      pb0 = *(const s16x8*)(bp);
      pb1 = *(const s16x8*)(bp + 8);
      pb2 = *(const s16x8*)(bp + 16);
      pb3 = *(const s16x8*)(bp + 24);
    }
    s16x8 af0 = *(const s16x8*)(Ab + aoff0);
    s16x8 af1 = *(const s16x8*)(Ab + aoff1);
    s16x8 bf0[4], bf1[4];
    for (int ni = 0; ni < 4; ni++) bf0[ni] = *(const s16x8*)(Bb + boff[ni][0]);
    for (int ni = 0; ni < 4; ni++) bf1[ni] = *(const s16x8*)(Bb + boff[ni][1]);
    for (int ni = 0; ni < 4; ni++) acc[ni] = mfma16(af0, bf0[ni], acc[ni]);
    for (int ni = 0; ni < 4; ni++) acc[ni] = mfma16(af1, bf1[ni], acc[ni]);
    __builtin_amdgcn_sched_barrier(0);
    __builtin_amdgcn_s_barrier();   // raw: no vmcnt drain, prefetch stays in flight
  }

  // epilogue: bias, bf16 X write, column sumsq partials
  for (int ni = 0; ni < 4; ni++) {
    int col = wn * 64 + ni * 16 + llo;
    float bv = bias[col];
    float s = 0.f;
    for (int r = 0; r < 4; r++) {
      float xv = acc[ni][r] + bv;
      s += xv * xv;
      X[(size_t)(row0 + wm * 16 + lhi * 4 + r) * D_ + col] = cvt_bf16(xv);
    }
    s += __shfl_xor(s, 16, 64);
    s += __shfl_xor(s, 32, 64);
    if (lhi == 0) psum[wm][col] = s;
  }
  __syncthreads();
  if (t < 128) ps[(size_t)bid * 128 + t] = psum[0][t] + psum[1][t];
}

// ---------------- K3: finalize norm + write bf16 V ----------------
// 1088 blocks, same row mapping as k_proj.
__global__ __launch_bounds__(256) void k_normfin(
    const short* __restrict__ Xq, const short* __restrict__ Xp, const short* __restrict__ Xn,
    const float* __restrict__ ps,
    short* __restrict__ Vq, short* __restrict__ Vp, short* __restrict__ Vn) {
  __shared__ float invs[128];
  int bid = blockIdx.x;
  const short* X; short* V; int row0, pbase, pcnt;
  if (bid < 64)       { X = Xq; V = Vq; row0 = bid * 32;         pbase = bid;                          pcnt = 1; }
  else if (bid < 576) { X = Xp; V = Vp; row0 = (bid - 64) * 32;  pbase = 64 + ((bid - 64) & ~7);       pcnt = 8; }
  else                { X = Xn; V = Vn; row0 = (bid - 576) * 32; pbase = 576 + ((bid - 576) & ~7);     pcnt = 8; }
  int t = threadIdx.x;
  if (t < 128) {
    float s = 0.f;
    for (int j = 0; j < pcnt; j++) s += ps[(size_t)(pbase + j) * 128 + t];
    invs[t] = 1.0f / fmaxf(sqrtf(s), 1e-12f);
  }
  __syncthreads();
  int row = row0 + (t >> 3), c0 = (t & 7) << 4;
  const short* xr = X + (size_t)row * D_ + c0;
  s16x8 x0 = *(const s16x8*)(xr);
  s16x8 x1 = *(const s16x8*)(xr + 8);
  f32x4 i0 = *(const f32x4*)(&invs[c0]);
  f32x4 i1 = *(const f32x4*)(&invs[c0 + 4]);
  f32x4 i2 = *(const f32x4*)(&invs[c0 + 8]);
  f32x4 i3 = *(const f32x4*)(&invs[c0 + 12]);
  s16x8 o0, o1;
  for (int j = 0; j < 4; j++) {
    o0[j]     = cvt_bf16(frombf(x0[j])     * i0[j]);
    o0[j + 4] = cvt_bf16(frombf(x0[j + 4]) * i1[j]);
    o1[j]     = cvt_bf16(frombf(x1[j])     * i2[j]);
    o1[j + 4] = cvt_bf16(frombf(x1[j + 4]) * i3[j]);
  }
  short* vr = V + (size_t)row * D_ + c0;
  *(s16x8*)(vr) = o0;
  *(s16x8*)(vr + 8) = o1;
}

// ---------------- K4: MaxSim, swapped operands (P=A in LDS, Q=B in regs) ----------------
// grid (64 c, 2 side, 4 q-quarter), 512 thr (8 waves). Wave owns 64 q-rows x all 256 p.
// max-over-p is lane-local -> no per-iter barriers, no cross-wave reduce.
__global__ __launch_bounds__(512, 2) void k_maxsim(
    const short* __restrict__ QV, const short* __restrict__ PV, const short* __restrict__ NV,
    const float* __restrict__ MF, float* __restrict__ OUT) {
  __shared__ short Ps[LP_ * D_];  // 64 KB, XOR-swizzled (pitch 256 B)
  int t = threadIdx.x, lane = t & 63, w = t >> 6;
  int lhi = lane >> 4, llo = lane & 15;
  int c = blockIdx.x, side = blockIdx.y, quarter = blockIdx.z;
  const short* P = side ? NV : PV;
  const float* mfb = MF + (size_t)(side * B_ + c) * LP_;

  // Q fragments (B operand): issue before staging barrier, they overlap
  const short* qb = QV + (size_t)(quarter * 512 + w * 64) * D_;
  s16x8 bq[4][4];
  for (int ni = 0; ni < 4; ni++)
    for (int ks = 0; ks < 4; ks++)
      bq[ni][ks] = *(const s16x8*)(qb + (size_t)(ni * 16 + llo) * D_ + ks * 32 + lhi * 8);

  const short* src = P + (size_t)c * LP_ * D_;
  for (int i = 0; i < 8; i++) {
    int s = i * 512 + t;
    int p = s >> 4, kc = s & 15;
    s16x8 v = *(const s16x8*)(src + (size_t)p * D_ + kc * 8);
    int byteoff = (p * 256 + kc * 16) ^ ((p & 7) << 4);
    *(s16x8*)((char*)Ps + byteoff) = v;
  }
  __syncthreads();

  float ninf = -__builtin_inff();
  float rmax[4] = {ninf, ninf, ninf, ninf};
  for (int pi = 0; pi < 4; pi++) {
    f32x4 acc[4][4] = {};  // [mi][ni]
    for (int ks = 0; ks < 4; ks++) {
      s16x8 pa[4];
      for (int mi = 0; mi < 4; mi++) {
        int prow = pi * 64 + mi * 16 + llo;
        int off = (prow * 256 + ks * 64 + lhi * 16) ^ ((prow & 7) << 4);
        pa[mi] = *(const s16x8*)((char*)Ps + off);
      }
      __builtin_amdgcn_s_setprio(1);
      for (int mi = 0; mi < 4; mi++)
        for (int ni = 0; ni < 4; ni++)
          acc[mi][ni] = mfma16(pa[mi], bq[ni][ks], acc[mi][ni]);
      __builtin_amdgcn_s_setprio(0);
    }
    f32x4 mk[4];
    for (int mi = 0; mi < 4; mi++)
      mk[mi] = *(const f32x4*)(mfb + pi * 64 + mi * 16 + lhi * 4);
    for (int ni = 0; ni < 4; ni++)
      for (int mi = 0; mi < 4; mi++)
        for (int r = 0; r < 4; r++)
          rmax[ni] = fmaxf(rmax[ni], acc[mi][ni][r] + mk[mi][r]);
  }
  // max across lhi groups (each lane then holds full-p max for q = ni*16+llo)
  for (int ni = 0; ni < 4; ni++) {
    rmax[ni] = fmaxf(rmax[ni], __shfl_xor(rmax[ni], 16, 64));
    rmax[ni] = fmaxf(rmax[ni], __shfl_xor(rmax[ni], 32, 64));
  }
  float s0 = rmax[0] + rmax[1];  // batch b0: q = llo and 16+llo
  float s1 = rmax[2] + rmax[3];  // batch b0+1
  for (int m = 1; m < 16; m <<= 1) {
    s0 += __shfl_xor(s0, m, 64);
    s1 += __shfl_xor(s1, m, 64);
  }
  if (lane == 0) {
    int b0 = quarter * 16 + w * 2;
    OUT[(size_t)b0 * 128 + side * 64 + c] = s0;
    OUT[(size_t)(b0 + 1) * 128 + side * 64 + c] = s1;
  }
}

extern "C" void kernel_launch(void* const* d_in, const int* in_sizes, int n_in,
                              void* d_out, int out_size, void* d_ws, size_t ws_size,
                              hipStream_t stream) {
  const float* qh = (const float*)d_in[0];
  const float* ph = (const float*)d_in[1];
  const float* nh = (const float*)d_in[2];
  const float* W  = (const float*)d_in[3];
  const float* bias = (const float*)d_in[4];
  const int* pm = (const int*)d_in[5];
  const int* nm = (const int*)d_in[6];
  float* out = (float*)d_out;
  char* ws = (char*)d_ws;

  short* Wt = (short*)(ws + 0x0);        // 128x768 bf16      192 KB
  float* mf = (float*)(ws + 0x30000);    // 2x64x256 f32      128 KB
  float* ps = (float*)(ws + 0x50000);    // 1088x128 f32      544 KB
  short* xq = (short*)(ws + 0xE0000);    // 2048x128 bf16     512 KB
  short* xp = (short*)(ws + 0x160000);   // 16384x128 bf16    4 MB
  short* xn = (short*)(ws + 0x560000);   // 16384x128 bf16    4 MB
  short* qv = (short*)(ws + 0x960000);   // 2048x128 bf16     512 KB
  short* pv = (short*)(ws + 0x9E0000);   // 16384x128 bf16    4 MB
  short* nv = (short*)(ws + 0xDE0000);   // 16384x128 bf16    4 MB

  k_pre<<<160, 256, 0, stream>>>(W, pm, nm, Wt, mf);
  k_proj<<<1088, 256, 0, stream>>>(qh, ph, nh, Wt, bias, xq, xp, xn, ps);
  k_normfin<<<1088, 256, 0, stream>>>(xq, xp, xn, ps, qv, pv, nv);
  k_maxsim<<<dim3(64, 2, 4), 512, 0, stream>>>(qv, pv, nv, mf, out);
}